// Round 9
// baseline (272.644 us; speedup 1.0000x reference)
//
#include <hip/hip_runtime.h>

// ContextTokenModel — round 18: resubmit of r17 dual-chain waves (r17 was an
// infra failure, not a measured regression). Hardening: 128-thread blocks of
// 2 independent waves (each wave = one dual-chain job), grid 256 — identical
// math and per-wave structure to r17.
// Design: wave = (pair, dir) owns btiles {2p, 2p+1} with shared weight frags
// and two fully independent chain states. 2x issue per wave, 2 jobs retired,
// no duplicated math, no barriers. r16 measured ~2/3 issue-bound + ~1/3
// stall -> dual-chain nets ~0.85x time per job plus stall fill.
// B=8192, T=21, D_in=160, H=32. Output fp32 [B,21,64] (fw|bw).

typedef __attribute__((ext_vector_type(8))) short short8;
typedef __attribute__((ext_vector_type(8))) __bf16 bf16x8;
typedef __attribute__((ext_vector_type(4))) float f32x4;
typedef unsigned short ushort_t;

// ---- bf16 cvt region (ushort offsets from ws+64) ----
#define U_TOKEMB  0             // 5000*128
#define U_TYPEMB  640000        // 5000*32
#define U_HOLE    800000        // 160
#define U_GKFW0   800160        // 192*64
#define U_GBFW0   812448        // 64
#define U_CKFW0   812512        // 192*32
#define U_CBFW0   818656        // 32
#define U_GKBW0   818688
#define U_GBBW0   830976
#define U_CKBW0   831040
#define U_CBBW0   837184
#define U_GKFW1   837216        // 96*64
#define U_GBFW1   843360
#define U_CKFW1   843424        // 96*32
#define U_CBFW1   846496
#define U_GKBW1   846528
#define U_GBBW1   852672
#define U_CKBW1   852736
#define U_CBBW1   855808
// cvt ends at 64 + 855840*2 = 1,711,744 B

#define Y0A_OFF   (4u << 20)    // y0a bf16 A-frags: uint4 [21*512][2][64] = 22,020,096 B
#define TYPF_OFF  (25u << 20)   // type-max bf16 A-frags: uint4 [20*512][64] = 10,485,760 B
#define WF_OFF    (37u << 20)   // swizzled weight B-frags: uint4 [108][64] = 110,592 B

__device__ __forceinline__ float bf2f(unsigned int u) {
  union { unsigned int i; float f; } v; v.i = u << 16; return v.f;
}
__device__ __forceinline__ unsigned short f2bf(float f) {
  unsigned int u = __float_as_uint(f);
  u += 0x7fffu + ((u >> 16) & 1u);
  return (unsigned short)(u >> 16);
}
__device__ __forceinline__ f32x4 mfma16(short8 a, short8 b, f32x4 c) {
  return __builtin_amdgcn_mfma_f32_16x16x32_bf16(
      __builtin_bit_cast(bf16x8, a), __builtin_bit_cast(bf16x8, b), c, 0, 0, 0);
}
__device__ __forceinline__ float sgm(float x) {
  x = fminf(fmaxf(x, -30.f), 30.f);
  return __fdividef(1.f, 1.f + __expf(-x));
}
__device__ __forceinline__ float tnh(float x) {
  x = fminf(fmaxf(x, -15.f), 15.f);
  float e = __expf(2.f * x);
  return (e - 1.f) * __fdividef(1.f, e + 1.f);
}

// ---------------------------------------------------------------------------
// k0 probes (validated in r8). flags[0]=fp32 floats; flags[1]=byte masks;
// flags[2]=types/mask slots swapped.
// ---------------------------------------------------------------------------
__global__ void k0_detect(const ushort_t* __restrict__ probe_f,
                          const unsigned* __restrict__ probe_m,
                          const unsigned* __restrict__ probe_t,
                          int* __restrict__ flags) {
  const int lane = threadIdx.x;  // 64
  int cnt = 0;
#pragma unroll
  for (int i = 0; i < 4; ++i) {
    unsigned e = ((unsigned)probe_f[lane + i * 64] >> 7) & 0xffu;
    if (e == 0u || (e >= 112u && e <= 134u)) cnt++;
  }
#pragma unroll
  for (int off = 32; off > 0; off >>= 1) cnt += __shfl_down(cnt, off, 64);
  const unsigned v = probe_m[lane];
  const unsigned long long bytelike =
      __ballot((v > 1u) && (v != 0x3F800000u) && ((v & 0xFEFEFEFEu) == 0u));
  const unsigned tv = probe_t[lane];
  const unsigned long long tlooksTypes =
      __ballot(!(tv == 0u || tv == 1u || tv == 0x3F800000u));
  if (lane == 0) {
    flags[0] = (cnt < 205) ? 1 : 0;
    flags[1] = bytelike ? 1 : 0;
    flags[2] = tlooksTypes ? 0 : 1;
  }
}

// ---------------------------------------------------------------------------
// kcvt: normalize all 19 float inputs to bf16 cvt region.
// ---------------------------------------------------------------------------
struct Cvt19 { const void* src[19]; int len[19]; int dst[19]; };

__global__ void kcvt(Cvt19 a, ushort_t* __restrict__ cvt, const int* __restrict__ flags) {
  const int fp32 = flags[0];
  int gid = blockIdx.x * blockDim.x + threadIdx.x;
#pragma unroll 1
  for (int s = 0; s < 19; ++s) {
    if (gid < a.len[s]) {
      cvt[a.dst[s] + gid] = fp32 ? f2bf(((const float*)a.src[s])[gid])
                                 : ((const ushort_t*)a.src[s])[gid];
      return;
    }
    gid -= a.len[s];
  }
}

// ---------------------------------------------------------------------------
// kswz: pre-swizzle all weight B-frags into per-lane uint4 layout (validated r14).
// L0 dir d: f<20: wg[kt=f>>2][tn=f&3]; 20..29: wc[kt=(f-20)>>1][tn=(f-20)&1];
// 30..33: wgh; 34..35: wch.  L1: f<12: wg; 12..17: wc.
// wf[(layer?72+d*18+f : d*36+f)*64+lane]
// ---------------------------------------------------------------------------
__global__ void kswz(const ushort_t* __restrict__ cvt, uint4* __restrict__ wf) {
  const int id = blockIdx.x * blockDim.x + threadIdx.x;
  if (id >= 108 * 64) return;
  const int frag = id >> 6, lane = id & 63;
  const int q = lane >> 4, nl = lane & 15;
  const int layer = (frag >= 72) ? 1 : 0;
  const int fr = layer ? frag - 72 : frag;
  const int nper = layer ? 18 : 36;
  const int d = fr / nper;
  const int f = fr - d * nper;
  const ushort_t* gk = layer ? (cvt + (d ? U_GKBW1 : U_GKFW1))
                             : (cvt + (d ? U_GKBW0 : U_GKFW0));
  const ushort_t* ck = layer ? (cvt + (d ? U_CKBW1 : U_CKFW1))
                             : (cvt + (d ? U_CKBW0 : U_CKFW0));
  const ushort_t* src; int row0, colw, coloff;
  if (!layer) {
    if (f < 20)      { src = gk; row0 = (f >> 2) * 32; colw = 64; coloff = (f & 3) * 16; }
    else if (f < 30) { int g = f - 20; src = ck; row0 = (g >> 1) * 32; colw = 32; coloff = (g & 1) * 16; }
    else if (f < 34) { src = gk; row0 = 160; colw = 64; coloff = (f - 30) * 16; }
    else             { src = ck; row0 = 160; colw = 32; coloff = (f - 34) * 16; }
  } else {
    if (f < 12)      { src = gk; row0 = (f >> 2) * 32; colw = 64; coloff = (f & 3) * 16; }
    else             { int g = f - 12; src = ck; row0 = (g >> 1) * 32; colw = 32; coloff = (g & 1) * 16; }
  }
  short8 v;
#pragma unroll
  for (int j = 0; j < 8; ++j)
    v[j] = (short)src[(row0 + q * 8 + j) * colw + coloff + nl];
  wf[frag * 64 + lane] = __builtin_bit_cast(uint4, v);
}

// ---------------------------------------------------------------------------
// ktypmax: masked type-embedding max, fully parallel (validated r11/r12).
// ---------------------------------------------------------------------------
__global__ __launch_bounds__(256) void ktypmax(
    const void* __restrict__ slot_tb, const void* __restrict__ slot_mb,
    const void* __restrict__ slot_ta, const void* __restrict__ slot_ma,
    const ushort_t* __restrict__ cvt, uint4* __restrict__ typf,
    const int* __restrict__ flags) {
  const int wv = threadIdx.x >> 6;
  const int lane = threadIdx.x & 63;
  const int q = lane >> 4, nl = lane & 15;
  const int job = blockIdx.x * 4 + wv;           // [0, 10240)
  const int st = job >> 9;                       // 0..19  (side*10+ts)
  const int btile = job & 511;
  const int side = (st >= 10) ? 1 : 0;
  const int ts = st - side * 10;
  const int b = btile * 16 + nl;
  const int sw = flags[2];
  const int bytem = flags[1];
  const int* tys = side ? (const int*)(sw ? slot_ma : slot_ta)
                        : (const int*)(sw ? slot_mb : slot_tb);
  const void* msk = side ? (sw ? slot_ta : slot_ma)
                         : (sw ? slot_tb : slot_mb);
  const int base = (b * 10 + ts) * 10;
  float mx[8];
#pragma unroll
  for (int j = 0; j < 8; ++j) mx[j] = -1e30f;
#pragma unroll
  for (int nt = 0; nt < 10; ++nt) {
    const int ty = tys[base + nt];
    const bool mv = bytem ? (((const unsigned char*)msk)[base + nt] != 0)
                          : (((const unsigned*)msk)[base + nt] != 0u);
    const float pen = mv ? 0.f : -1000.f;
    uint4 e = *reinterpret_cast<const uint4*>(cvt + U_TYPEMB + (size_t)ty * 32 + q * 8);
    const unsigned w[4] = {e.x, e.y, e.z, e.w};
#pragma unroll
    for (int j2 = 0; j2 < 4; ++j2) {
      mx[2 * j2]     = fmaxf(mx[2 * j2],     bf2f(w[j2] & 0xffffu) + pen);
      mx[2 * j2 + 1] = fmaxf(mx[2 * j2 + 1], bf2f(w[j2] >> 16) + pen);
    }
  }
  short8 v;
#pragma unroll
  for (int j = 0; j < 8; ++j) v[j] = (short)f2bf(mx[j]);
  typf[(size_t)job * 64 + lane] = __builtin_bit_cast(uint4, v);
}

// ---------------------------------------------------------------------------
// x-gather (r13-validated): token-embedding frags + one precomputed typf load.
// ---------------------------------------------------------------------------
__device__ __forceinline__ void gatherX(
    int t, int btile, int lane,
    const int* __restrict__ tok_b, const int* __restrict__ tok_a,
    const ushort_t* __restrict__ cvt, const uint4* __restrict__ typf,
    short8 af[5]) {
  const int q = lane >> 4, nl = lane & 15;
  if (t == 10) {
#pragma unroll
    for (int kt = 0; kt < 5; ++kt)
      af[kt] = __builtin_bit_cast(short8,
          *reinterpret_cast<const uint4*>(cvt + U_HOLE + kt * 32 + q * 8));
    return;
  }
  const int ts = (t < 10) ? t : t - 11;
  const int side = (t < 10) ? 0 : 1;
  const int b = btile * 16 + nl;
  const int tok = (side ? tok_a : tok_b)[b * 10 + ts];
#pragma unroll
  for (int kt = 0; kt < 4; ++kt)
    af[kt] = __builtin_bit_cast(short8,
        *reinterpret_cast<const uint4*>(cvt + U_TOKEMB + (size_t)tok * 128 + kt * 32 + q * 8));
  af[4] = __builtin_bit_cast(short8,
      typf[((size_t)(side * 10 + ts) * 512 + btile) * 64 + lane]);
}

// ---------------------------------------------------------------------------
// krec0: layer-0 fused projection+recurrence, DUAL-CHAIN waves.
// 256 blocks x 2 waves; wave = (pair, dir) handles btiles {2p, 2p+1} with
// shared weights and two fully independent chain states. No barriers.
// ---------------------------------------------------------------------------
__global__ __launch_bounds__(128, 1) void krec0(
    const int* __restrict__ tok_b, const int* __restrict__ tok_a,
    const ushort_t* __restrict__ cvt, const uint4* __restrict__ wf,
    const uint4* __restrict__ typf, uint4* __restrict__ y0a) {
  __shared__ __align__(16) ushort_t hbuf[2][2][2][16 * 40];
  const int wv = threadIdx.x >> 6;
  const int lane = threadIdx.x & 63;
  const int q = lane >> 4, nl = lane & 15;
  const int job = blockIdx.x * 2 + wv;     // [0, 512)
  const int dir = job & 1, pair = job >> 1;

  const uint4* wfL0 = wf + dir * 36 * 64;
  short8 wg[5][4], wc[5][2], wgh[4], wch[2];
#pragma unroll
  for (int kt = 0; kt < 5; ++kt) {
#pragma unroll
    for (int tn = 0; tn < 4; ++tn)
      wg[kt][tn] = __builtin_bit_cast(short8, wfL0[(kt * 4 + tn) * 64 + lane]);
#pragma unroll
    for (int tn = 0; tn < 2; ++tn)
      wc[kt][tn] = __builtin_bit_cast(short8, wfL0[(20 + kt * 2 + tn) * 64 + lane]);
  }
#pragma unroll
  for (int tn = 0; tn < 4; ++tn)
    wgh[tn] = __builtin_bit_cast(short8, wfL0[(30 + tn) * 64 + lane]);
#pragma unroll
  for (int tn = 0; tn < 2; ++tn)
    wch[tn] = __builtin_bit_cast(short8, wfL0[(34 + tn) * 64 + lane]);

  const ushort_t* gb = cvt + (dir ? U_GBBW0 : U_GBFW0);
  const ushort_t* cb = cvt + (dir ? U_CBBW0 : U_CBFW0);
  float gb4[4], cb4[2];
#pragma unroll
  for (int tn = 0; tn < 4; ++tn) gb4[tn] = bf2f((unsigned)gb[tn * 16 + nl]);
#pragma unroll
  for (int tn = 0; tn < 2; ++tn) cb4[tn] = bf2f((unsigned)cb[tn * 16 + nl]);

  f32x4 hc0[2], hc1[2];
  short8 hA[2];
#pragma unroll
  for (int c = 0; c < 2; ++c) {
    hc0[c] = (f32x4){0.f, 0.f, 0.f, 0.f};
    hc1[c] = (f32x4){0.f, 0.f, 0.f, 0.f};
    hA[c] = (short8){0, 0, 0, 0, 0, 0, 0, 0};
  }

  short8 afc[2][5], afn[2][5];
#pragma unroll
  for (int c = 0; c < 2; ++c)
    gatherX(dir ? 20 : 0, pair * 2 + c, lane, tok_b, tok_a, cvt, typf, afc[c]);

  for (int s = 0; s < 21; ++s) {
    const int t = dir ? 20 - s : s;
    if (s < 20) {
#pragma unroll
      for (int c = 0; c < 2; ++c)
        gatherX(dir ? t - 1 : t + 1, pair * 2 + c, lane, tok_b, tok_a, cvt, typf, afn[c]);
    }

    // gates (both chains interleaved, shared weights)
    f32x4 ru[2][4];
#pragma unroll
    for (int tn = 0; tn < 4; ++tn)
#pragma unroll
      for (int c = 0; c < 2; ++c) {
        f32x4 acc = {gb4[tn], gb4[tn], gb4[tn], gb4[tn]};
#pragma unroll
        for (int kt = 0; kt < 5; ++kt) acc = mfma16(afc[c][kt], wg[kt][tn], acc);
        acc = mfma16(hA[c], wgh[tn], acc);
        ru[c][tn] = acc;
      }
#pragma unroll
    for (int c = 0; c < 2; ++c)
#pragma unroll
      for (int tn = 0; tn < 4; ++tn)
#pragma unroll
        for (int r = 0; r < 4; ++r) ru[c][tn][r] = sgm(ru[c][tn][r]);

    // r*h -> A-layout via per-chain LDS (no barrier; same-wave ordering)
#pragma unroll
    for (int c = 0; c < 2; ++c)
#pragma unroll
      for (int r = 0; r < 4; ++r) {
        hbuf[wv][c][0][(q * 4 + r) * 40 + nl]      = f2bf(ru[c][0][r] * hc0[c][r]);
        hbuf[wv][c][0][(q * 4 + r) * 40 + 16 + nl] = f2bf(ru[c][1][r] * hc1[c][r]);
      }
    short8 rhA[2];
#pragma unroll
    for (int c = 0; c < 2; ++c)
      rhA[c] = *reinterpret_cast<const short8*>(&hbuf[wv][c][0][nl * 40 + q * 8]);

    // candidate
    f32x4 cc0[2], cc1[2];
#pragma unroll
    for (int c = 0; c < 2; ++c) {
      f32x4 a0 = {cb4[0], cb4[0], cb4[0], cb4[0]};
      f32x4 a1 = {cb4[1], cb4[1], cb4[1], cb4[1]};
#pragma unroll
      for (int kt = 0; kt < 5; ++kt) {
        a0 = mfma16(afc[c][kt], wc[kt][0], a0);
        a1 = mfma16(afc[c][kt], wc[kt][1], a1);
      }
      a0 = mfma16(rhA[c], wch[0], a0);
      a1 = mfma16(rhA[c], wch[1], a1);
      cc0[c] = a0; cc1[c] = a1;
    }
#pragma unroll
    for (int c = 0; c < 2; ++c)
#pragma unroll
      for (int r = 0; r < 4; ++r) {
        const float c0 = tnh(cc0[c][r]), c1 = tnh(cc1[c][r]);
        const float u0 = ru[c][2][r], u1 = ru[c][3][r];
        hc0[c][r] = u0 * hc0[c][r] + (1.f - u0) * c0;
        hc1[c][r] = u1 * hc1[c][r] + (1.f - u1) * c1;
      }

    // h' -> A-layout (next operand + y0 output)
#pragma unroll
    for (int c = 0; c < 2; ++c)
#pragma unroll
      for (int r = 0; r < 4; ++r) {
        hbuf[wv][c][1][(q * 4 + r) * 40 + nl]      = f2bf(hc0[c][r]);
        hbuf[wv][c][1][(q * 4 + r) * 40 + 16 + nl] = f2bf(hc1[c][r]);
      }
#pragma unroll
    for (int c = 0; c < 2; ++c) {
      hA[c] = *reinterpret_cast<const short8*>(&hbuf[wv][c][1][nl * 40 + q * 8]);
      y0a[((size_t)(t * 512 + pair * 2 + c) * 2 + dir) * 64 + lane] =
          __builtin_bit_cast(uint4, hA[c]);
    }

    if (s < 20) {
#pragma unroll
      for (int c = 0; c < 2; ++c)
#pragma unroll
        for (int kt = 0; kt < 5; ++kt) afc[c][kt] = afn[c][kt];
    }
  }
}

// ---------------------------------------------------------------------------
// k3b: layer-1 recurrence, DUAL-CHAIN waves; FP32 output [b][21][64].
// Same accumulation order as the validated r13 k3b (bias, ya0, ya1, hA).
// ---------------------------------------------------------------------------
__global__ __launch_bounds__(128, 1) void k3b(
    const ushort_t* __restrict__ cvt, const uint4* __restrict__ wf,
    const uint4* __restrict__ y0a, float* __restrict__ out) {
  __shared__ __align__(16) ushort_t hbuf[2][2][2][16 * 40];
  const int wv = threadIdx.x >> 6;
  const int lane = threadIdx.x & 63;
  const int q = lane >> 4, nl = lane & 15;
  const int job = blockIdx.x * 2 + wv;     // [0, 512)
  const int dir = job & 1, pair = job >> 1;

  const uint4* wfL1 = wf + (72 + dir * 18) * 64;
  short8 wgx0[4], wgx1[4], wgh[4], wcx0[2], wcx1[2], wch[2];
#pragma unroll
  for (int tn = 0; tn < 4; ++tn) {
    wgx0[tn] = __builtin_bit_cast(short8, wfL1[tn * 64 + lane]);
    wgx1[tn] = __builtin_bit_cast(short8, wfL1[(4 + tn) * 64 + lane]);
    wgh[tn]  = __builtin_bit_cast(short8, wfL1[(8 + tn) * 64 + lane]);
  }
#pragma unroll
  for (int tn = 0; tn < 2; ++tn) {
    wcx0[tn] = __builtin_bit_cast(short8, wfL1[(12 + tn) * 64 + lane]);
    wcx1[tn] = __builtin_bit_cast(short8, wfL1[(14 + tn) * 64 + lane]);
    wch[tn]  = __builtin_bit_cast(short8, wfL1[(16 + tn) * 64 + lane]);
  }
  const ushort_t* gb = cvt + (dir ? U_GBBW1 : U_GBFW1);
  const ushort_t* cb = cvt + (dir ? U_CBBW1 : U_CBFW1);
  float gb4[4], cb4[2];
#pragma unroll
  for (int tn = 0; tn < 4; ++tn) gb4[tn] = bf2f((unsigned)gb[tn * 16 + nl]);
#pragma unroll
  for (int tn = 0; tn < 2; ++tn) cb4[tn] = bf2f((unsigned)cb[tn * 16 + nl]);

  f32x4 hc0[2], hc1[2];
  short8 hA[2];
#pragma unroll
  for (int c = 0; c < 2; ++c) {
    hc0[c] = (f32x4){0.f, 0.f, 0.f, 0.f};
    hc1[c] = (f32x4){0.f, 0.f, 0.f, 0.f};
    hA[c] = (short8){0, 0, 0, 0, 0, 0, 0, 0};
  }

  short8 ya0[2], ya1[2], yn0[2], yn1[2];
  {
    const int t0 = dir ? 20 : 0;
#pragma unroll
    for (int c = 0; c < 2; ++c) {
      const int bt = pair * 2 + c;
      ya0[c] = __builtin_bit_cast(short8, y0a[((size_t)(t0 * 512 + bt) * 2 + 0) * 64 + lane]);
      ya1[c] = __builtin_bit_cast(short8, y0a[((size_t)(t0 * 512 + bt) * 2 + 1) * 64 + lane]);
    }
  }

  for (int s = 0; s < 21; ++s) {
    const int t = dir ? 20 - s : s;
    if (s < 20) {
      const int t2 = dir ? t - 1 : t + 1;
#pragma unroll
      for (int c = 0; c < 2; ++c) {
        const int bt = pair * 2 + c;
        yn0[c] = __builtin_bit_cast(short8, y0a[((size_t)(t2 * 512 + bt) * 2 + 0) * 64 + lane]);
        yn1[c] = __builtin_bit_cast(short8, y0a[((size_t)(t2 * 512 + bt) * 2 + 1) * 64 + lane]);
      }
    }

    f32x4 ru[2][4];
#pragma unroll
    for (int tn = 0; tn < 4; ++tn)
#pragma unroll
      for (int c = 0; c < 2; ++c) {
        f32x4 acc = {gb4[tn], gb4[tn], gb4[tn], gb4[tn]};
        acc = mfma16(ya0[c], wgx0[tn], acc);
        acc = mfma16(ya1[c], wgx1[tn], acc);
        acc = mfma16(hA[c],  wgh[tn], acc);
        ru[c][tn] = acc;
      }
#pragma unroll
    for (int c = 0; c < 2; ++c)
#pragma unroll
      for (int tn = 0; tn < 4; ++tn)
#pragma unroll
        for (int r = 0; r < 4; ++r) ru[c][tn][r] = sgm(ru[c][tn][r]);

#pragma unroll
    for (int c = 0; c < 2; ++c)
#pragma unroll
      for (int r = 0; r < 4; ++r) {
        hbuf[wv][c][0][(q * 4 + r) * 40 + nl]      = f2bf(ru[c][0][r] * hc0[c][r]);
        hbuf[wv][c][0][(q * 4 + r) * 40 + 16 + nl] = f2bf(ru[c][1][r] * hc1[c][r]);
      }
    short8 rhA[2];
#pragma unroll
    for (int c = 0; c < 2; ++c)
      rhA[c] = *reinterpret_cast<const short8*>(&hbuf[wv][c][0][nl * 40 + q * 8]);

    f32x4 cc0[2], cc1[2];
#pragma unroll
    for (int c = 0; c < 2; ++c) {
      f32x4 a0 = {cb4[0], cb4[0], cb4[0], cb4[0]};
      a0 = mfma16(ya0[c], wcx0[0], a0);
      a0 = mfma16(ya1[c], wcx1[0], a0);
      a0 = mfma16(rhA[c], wch[0], a0);
      f32x4 a1 = {cb4[1], cb4[1], cb4[1], cb4[1]};
      a1 = mfma16(ya0[c], wcx0[1], a1);
      a1 = mfma16(ya1[c], wcx1[1], a1);
      a1 = mfma16(rhA[c], wch[1], a1);
      cc0[c] = a0; cc1[c] = a1;
    }
#pragma unroll
    for (int c = 0; c < 2; ++c)
#pragma unroll
      for (int r = 0; r < 4; ++r) {
        const float c0 = tnh(cc0[c][r]), c1 = tnh(cc1[c][r]);
        const float u0 = ru[c][2][r], u1 = ru[c][3][r];
        hc0[c][r] = u0 * hc0[c][r] + (1.f - u0) * c0;
        hc1[c][r] = u1 * hc1[c][r] + (1.f - u1) * c1;
      }

#pragma unroll
    for (int c = 0; c < 2; ++c)
#pragma unroll
      for (int r = 0; r < 4; ++r) {
        hbuf[wv][c][1][(q * 4 + r) * 40 + nl]      = f2bf(hc0[c][r]);
        hbuf[wv][c][1][(q * 4 + r) * 40 + 16 + nl] = f2bf(hc1[c][r]);
      }
#pragma unroll
    for (int c = 0; c < 2; ++c)
      hA[c] = *reinterpret_cast<const short8*>(&hbuf[wv][c][1][nl * 40 + q * 8]);

    // FP32 output: lane holds h'[m=q*4+r][ch nl and 16+nl] per chain
#pragma unroll
    for (int c = 0; c < 2; ++c)
#pragma unroll
      for (int r = 0; r < 4; ++r) {
        const size_t o =
            ((size_t)((pair * 2 + c) * 16 + q * 4 + r) * 21 + t) * 64 + dir * 32 + nl;
        out[o]      = hc0[c][r];
        out[o + 16] = hc1[c][r];
      }

    if (s < 20) {
#pragma unroll
      for (int c = 0; c < 2; ++c) { ya0[c] = yn0[c]; ya1[c] = yn1[c]; }
    }
  }
}

// ---------------------------------------------------------------------------
extern "C" void kernel_launch(void* const* d_in, const int* in_sizes, int n_in,
                              void* d_out, int out_size, void* d_ws, size_t ws_size,
                              hipStream_t stream)
{
  const int* tok_b = (const int*)d_in[0];
  const void* slot_tb = d_in[1];
  const void* slot_mb = d_in[2];
  const int* tok_a = (const int*)d_in[3];
  const void* slot_ta = d_in[4];
  const void* slot_ma = d_in[5];

  int* flags = (int*)d_ws;
  ushort_t* cvt = (ushort_t*)((char*)d_ws + 64);
  uint4* y0a = (uint4*)((char*)d_ws + Y0A_OFF);
  uint4* typf = (uint4*)((char*)d_ws + TYPF_OFF);
  uint4* wf  = (uint4*)((char*)d_ws + WF_OFF);

  k0_detect<<<dim3(1), dim3(64), 0, stream>>>(
      (const ushort_t*)d_in[6], (const unsigned*)slot_mb, (const unsigned*)slot_tb,
      flags);

  static const int slen[19] = {640000, 160000, 160,
                               12288, 64, 6144, 32, 12288, 64, 6144, 32,
                               6144, 64, 3072, 32, 6144, 64, 3072, 32};
  static const int sdst[19] = {U_TOKEMB, U_TYPEMB, U_HOLE,
                               U_GKFW0, U_GBFW0, U_CKFW0, U_CBFW0,
                               U_GKBW0, U_GBBW0, U_CKBW0, U_CBBW0,
                               U_GKFW1, U_GBFW1, U_CKFW1, U_CBFW1,
                               U_GKBW1, U_GBBW1, U_CKBW1, U_CBBW1};
  Cvt19 a;
  int tot = 0;
  for (int i = 0; i < 19; ++i) {
    a.src[i] = d_in[6 + i]; a.len[i] = slen[i]; a.dst[i] = sdst[i]; tot += slen[i];
  }
  kcvt<<<dim3((tot + 255) / 256), dim3(256), 0, stream>>>(a, cvt, flags);

  kswz<<<dim3(27), dim3(256), 0, stream>>>(cvt, wf);

  ktypmax<<<dim3(2560), dim3(256), 0, stream>>>(
      slot_tb, slot_mb, slot_ta, slot_ma, cvt, typf, flags);

  krec0<<<dim3(256), dim3(128), 0, stream>>>(tok_b, tok_a, cvt, wf, typf, y0a);

  k3b<<<dim3(256), dim3(128), 0, stream>>>(cvt, wf, y0a, (float*)d_out);
}

// Round 10
// 188.057 us; speedup vs baseline: 1.4498x; 1.4498x over previous
//
#include <hip/hip_runtime.h>

// ContextTokenModel — round 19: instruction diet on the r13 structure (best
// verified, 212 µs). r16/r18 scaling tests: doubling per-SIMD issue -> 1.7x
// wall, both via 2 waves/SIMD and via 2 chains/wave => ~70% issue-bound with
// all SIMDs active. Diet:
//  (a) activations: full IEEE divisions (24/step, ~9 ops each) -> v_rcp_f32
//      via __builtin_amdgcn_rcpf; tnh = 1-2*rcp(e+1) needs NO clamps
//      (inf -> exact +-1). sgm = rcp(1+exp(-x)), also clamp-free.
//  (b) transposes: channel k-order permuted by pi(2i)=i, pi(2i+1)=16+i on
//      BOTH the LDS layout and the matching B-frag rows (kswz) -> each lane
//      packs (ch nl, ch 16+nl) with one v_cvt_pk_bf16_f32 + one ds_write_b32
//      (was 2 f2bf x4ops + 2 ds_write_b16). pi is absorbed into single-MFMA
//      k-order: y0a, rh, h all consistent across krec0/k3b.
// B=8192, T=21, D_in=160, H=32. Output fp32 [B,21,64] (fw|bw).

typedef __attribute__((ext_vector_type(8))) short short8;
typedef __attribute__((ext_vector_type(8))) __bf16 bf16x8;
typedef __attribute__((ext_vector_type(4))) float f32x4;
typedef unsigned short ushort_t;

// ---- bf16 cvt region (ushort offsets from ws+64) ----
#define U_TOKEMB  0             // 5000*128
#define U_TYPEMB  640000        // 5000*32
#define U_HOLE    800000        // 160
#define U_GKFW0   800160        // 192*64
#define U_GBFW0   812448        // 64
#define U_CKFW0   812512        // 192*32
#define U_CBFW0   818656        // 32
#define U_GKBW0   818688
#define U_GBBW0   830976
#define U_CKBW0   831040
#define U_CBBW0   837184
#define U_GKFW1   837216        // 96*64
#define U_GBFW1   843360
#define U_CKFW1   843424        // 96*32
#define U_CBFW1   846496
#define U_GKBW1   846528
#define U_GBBW1   852672
#define U_CKBW1   852736
#define U_CBBW1   855808
// cvt ends at 64 + 855840*2 = 1,711,744 B

#define Y0A_OFF   (4u << 20)    // y0a bf16 A-frags: uint4 [21*512][2][64] = 22,020,096 B
#define TYPF_OFF  (25u << 20)   // type-max bf16 A-frags: uint4 [20*512][64] = 10,485,760 B
#define WF_OFF    (37u << 20)   // swizzled weight B-frags: uint4 [108][64] = 110,592 B

__device__ __forceinline__ float bf2f(unsigned int u) {
  union { unsigned int i; float f; } v; v.i = u << 16; return v.f;
}
__device__ __forceinline__ unsigned short f2bf(float f) {
  unsigned int u = __float_as_uint(f);
  u += 0x7fffu + ((u >> 16) & 1u);
  return (unsigned short)(u >> 16);
}
// pack 2 floats -> 2 bf16 (RNE, = f2bf bits): lo = cvt(a), hi = cvt(b)
__device__ __forceinline__ unsigned cvtpk(float a, float b) {
  unsigned r;
  asm("v_cvt_pk_bf16_f32 %0, %1, %2" : "=v"(r) : "v"(a), "v"(b));
  return r;
}
__device__ __forceinline__ f32x4 mfma16(short8 a, short8 b, f32x4 c) {
  return __builtin_amdgcn_mfma_f32_16x16x32_bf16(
      __builtin_bit_cast(bf16x8, a), __builtin_bit_cast(bf16x8, b), c, 0, 0, 0);
}
__device__ __forceinline__ float frcp(float x) { return __builtin_amdgcn_rcpf(x); }
__device__ __forceinline__ float sgm(float x) {
  return frcp(1.f + __expf(-x));          // x->-inf: exp=inf, rcp=0; x->+inf: 1
}
__device__ __forceinline__ float tnh(float x) {
  return 1.f - 2.f * frcp(__expf(2.f * x) + 1.f);  // inf-safe: -> +-1 exactly
}
// k-slot permutation for h/y channel spaces: slot p holds channel pi(p)
__device__ __forceinline__ int PIk(int p) { return (p >> 1) + ((p & 1) << 4); }

// ---------------------------------------------------------------------------
// k0 probes (validated in r8). flags[0]=fp32 floats; flags[1]=byte masks;
// flags[2]=types/mask slots swapped.
// ---------------------------------------------------------------------------
__global__ void k0_detect(const ushort_t* __restrict__ probe_f,
                          const unsigned* __restrict__ probe_m,
                          const unsigned* __restrict__ probe_t,
                          int* __restrict__ flags) {
  const int lane = threadIdx.x;  // 64
  int cnt = 0;
#pragma unroll
  for (int i = 0; i < 4; ++i) {
    unsigned e = ((unsigned)probe_f[lane + i * 64] >> 7) & 0xffu;
    if (e == 0u || (e >= 112u && e <= 134u)) cnt++;
  }
#pragma unroll
  for (int off = 32; off > 0; off >>= 1) cnt += __shfl_down(cnt, off, 64);
  const unsigned v = probe_m[lane];
  const unsigned long long bytelike =
      __ballot((v > 1u) && (v != 0x3F800000u) && ((v & 0xFEFEFEFEu) == 0u));
  const unsigned tv = probe_t[lane];
  const unsigned long long tlooksTypes =
      __ballot(!(tv == 0u || tv == 1u || tv == 0x3F800000u));
  if (lane == 0) {
    flags[0] = (cnt < 205) ? 1 : 0;
    flags[1] = bytelike ? 1 : 0;
    flags[2] = tlooksTypes ? 0 : 1;
  }
}

// ---------------------------------------------------------------------------
// kcvt: normalize all 19 float inputs to bf16 cvt region.
// ---------------------------------------------------------------------------
struct Cvt19 { const void* src[19]; int len[19]; int dst[19]; };

__global__ void kcvt(Cvt19 a, ushort_t* __restrict__ cvt, const int* __restrict__ flags) {
  const int fp32 = flags[0];
  int gid = blockIdx.x * blockDim.x + threadIdx.x;
#pragma unroll 1
  for (int s = 0; s < 19; ++s) {
    if (gid < a.len[s]) {
      cvt[a.dst[s] + gid] = fp32 ? f2bf(((const float*)a.src[s])[gid])
                                 : ((const ushort_t*)a.src[s])[gid];
      return;
    }
    gid -= a.len[s];
  }
}

// ---------------------------------------------------------------------------
// kswz: pre-swizzle all weight B-frags into per-lane uint4 layout.
// h/y-space frags use pi-permuted k rows (must match the packed LDS layout):
//  L0: f 30..33 wgh, 34..35 wch -> row 160 + pi(p).
//  L1: ALL frags (k-spaces = y0_fw | y0_bw | h, all pi-packed) -> row0 + pi(p).
// x-space frags (L0 f<30) unpermuted.
// ---------------------------------------------------------------------------
__global__ void kswz(const ushort_t* __restrict__ cvt, uint4* __restrict__ wf) {
  const int id = blockIdx.x * blockDim.x + threadIdx.x;
  if (id >= 108 * 64) return;
  const int frag = id >> 6, lane = id & 63;
  const int q = lane >> 4, nl = lane & 15;
  const int layer = (frag >= 72) ? 1 : 0;
  const int fr = layer ? frag - 72 : frag;
  const int nper = layer ? 18 : 36;
  const int d = fr / nper;
  const int f = fr - d * nper;
  const ushort_t* gk = layer ? (cvt + (d ? U_GKBW1 : U_GKFW1))
                             : (cvt + (d ? U_GKBW0 : U_GKFW0));
  const ushort_t* ck = layer ? (cvt + (d ? U_CKBW1 : U_CKFW1))
                             : (cvt + (d ? U_CKBW0 : U_CKFW0));
  const ushort_t* src; int row0, colw, coloff; bool perm;
  if (!layer) {
    if (f < 20)      { src = gk; row0 = (f >> 2) * 32; colw = 64; coloff = (f & 3) * 16; perm = false; }
    else if (f < 30) { int g = f - 20; src = ck; row0 = (g >> 1) * 32; colw = 32; coloff = (g & 1) * 16; perm = false; }
    else if (f < 34) { src = gk; row0 = 160; colw = 64; coloff = (f - 30) * 16; perm = true; }
    else             { src = ck; row0 = 160; colw = 32; coloff = (f - 34) * 16; perm = true; }
  } else {
    perm = true;
    if (f < 12)      { src = gk; row0 = (f >> 2) * 32; colw = 64; coloff = (f & 3) * 16; }
    else             { int g = f - 12; src = ck; row0 = (g >> 1) * 32; colw = 32; coloff = (g & 1) * 16; }
  }
  short8 v;
#pragma unroll
  for (int j = 0; j < 8; ++j) {
    const int p = q * 8 + j;
    const int row = row0 + (perm ? PIk(p) : p);
    v[j] = (short)src[row * colw + coloff + nl];
  }
  wf[frag * 64 + lane] = __builtin_bit_cast(uint4, v);
}

// ---------------------------------------------------------------------------
// ktypmax: masked type-embedding max, fully parallel (validated r11/r12).
// ---------------------------------------------------------------------------
__global__ __launch_bounds__(256) void ktypmax(
    const void* __restrict__ slot_tb, const void* __restrict__ slot_mb,
    const void* __restrict__ slot_ta, const void* __restrict__ slot_ma,
    const ushort_t* __restrict__ cvt, uint4* __restrict__ typf,
    const int* __restrict__ flags) {
  const int wv = threadIdx.x >> 6;
  const int lane = threadIdx.x & 63;
  const int q = lane >> 4, nl = lane & 15;
  const int job = blockIdx.x * 4 + wv;           // [0, 10240)
  const int st = job >> 9;                       // 0..19  (side*10+ts)
  const int btile = job & 511;
  const int side = (st >= 10) ? 1 : 0;
  const int ts = st - side * 10;
  const int b = btile * 16 + nl;
  const int sw = flags[2];
  const int bytem = flags[1];
  const int* tys = side ? (const int*)(sw ? slot_ma : slot_ta)
                        : (const int*)(sw ? slot_mb : slot_tb);
  const void* msk = side ? (sw ? slot_ta : slot_ma)
                         : (sw ? slot_tb : slot_mb);
  const int base = (b * 10 + ts) * 10;
  float mx[8];
#pragma unroll
  for (int j = 0; j < 8; ++j) mx[j] = -1e30f;
#pragma unroll
  for (int nt = 0; nt < 10; ++nt) {
    const int ty = tys[base + nt];
    const bool mv = bytem ? (((const unsigned char*)msk)[base + nt] != 0)
                          : (((const unsigned*)msk)[base + nt] != 0u);
    const float pen = mv ? 0.f : -1000.f;
    uint4 e = *reinterpret_cast<const uint4*>(cvt + U_TYPEMB + (size_t)ty * 32 + q * 8);
    const unsigned w[4] = {e.x, e.y, e.z, e.w};
#pragma unroll
    for (int j2 = 0; j2 < 4; ++j2) {
      mx[2 * j2]     = fmaxf(mx[2 * j2],     bf2f(w[j2] & 0xffffu) + pen);
      mx[2 * j2 + 1] = fmaxf(mx[2 * j2 + 1], bf2f(w[j2] >> 16) + pen);
    }
  }
  short8 v;
#pragma unroll
  for (int j = 0; j < 8; ++j) v[j] = (short)f2bf(mx[j]);
  typf[(size_t)job * 64 + lane] = __builtin_bit_cast(uint4, v);
}

// ---------------------------------------------------------------------------
// x-gather (r13-validated): token-embedding frags + one precomputed typf load.
// ---------------------------------------------------------------------------
__device__ __forceinline__ void gatherX(
    int t, int btile, int lane,
    const int* __restrict__ tok_b, const int* __restrict__ tok_a,
    const ushort_t* __restrict__ cvt, const uint4* __restrict__ typf,
    short8 af[5]) {
  const int q = lane >> 4, nl = lane & 15;
  if (t == 10) {
#pragma unroll
    for (int kt = 0; kt < 5; ++kt)
      af[kt] = __builtin_bit_cast(short8,
          *reinterpret_cast<const uint4*>(cvt + U_HOLE + kt * 32 + q * 8));
    return;
  }
  const int ts = (t < 10) ? t : t - 11;
  const int side = (t < 10) ? 0 : 1;
  const int b = btile * 16 + nl;
  const int tok = (side ? tok_a : tok_b)[b * 10 + ts];
#pragma unroll
  for (int kt = 0; kt < 4; ++kt)
    af[kt] = __builtin_bit_cast(short8,
        *reinterpret_cast<const uint4*>(cvt + U_TOKEMB + (size_t)tok * 128 + kt * 32 + q * 8));
  af[4] = __builtin_bit_cast(short8,
      typf[((size_t)(side * 10 + ts) * 512 + btile) * 64 + lane]);
}

// ---------------------------------------------------------------------------
// krec0: layer-0 fused projection+recurrence (r13 structure: 1024 wave-jobs,
// 1 wave per job, no barriers) + diet: rcp activations, cvt_pk packed
// transposes (pi k-order).
// ---------------------------------------------------------------------------
__global__ __launch_bounds__(256, 1) void krec0(
    const int* __restrict__ tok_b, const int* __restrict__ tok_a,
    const ushort_t* __restrict__ cvt, const uint4* __restrict__ wf,
    const uint4* __restrict__ typf, uint4* __restrict__ y0a) {
  __shared__ __align__(16) ushort_t hbuf[4][2][16 * 40];
  const int wv = threadIdx.x >> 6;
  const int lane = threadIdx.x & 63;
  const int q = lane >> 4, nl = lane & 15;
  const int job = blockIdx.x * 4 + wv;
  const int dir = job & 1, btile = job >> 1;

  const uint4* wfL0 = wf + dir * 36 * 64;
  short8 wg[5][4], wc[5][2], wgh[4], wch[2];
#pragma unroll
  for (int kt = 0; kt < 5; ++kt) {
#pragma unroll
    for (int tn = 0; tn < 4; ++tn)
      wg[kt][tn] = __builtin_bit_cast(short8, wfL0[(kt * 4 + tn) * 64 + lane]);
#pragma unroll
    for (int tn = 0; tn < 2; ++tn)
      wc[kt][tn] = __builtin_bit_cast(short8, wfL0[(20 + kt * 2 + tn) * 64 + lane]);
  }
#pragma unroll
  for (int tn = 0; tn < 4; ++tn)
    wgh[tn] = __builtin_bit_cast(short8, wfL0[(30 + tn) * 64 + lane]);
#pragma unroll
  for (int tn = 0; tn < 2; ++tn)
    wch[tn] = __builtin_bit_cast(short8, wfL0[(34 + tn) * 64 + lane]);

  const ushort_t* gb = cvt + (dir ? U_GBBW0 : U_GBFW0);
  const ushort_t* cb = cvt + (dir ? U_CBBW0 : U_CBFW0);
  float gb4[4], cb4[2];
#pragma unroll
  for (int tn = 0; tn < 4; ++tn) gb4[tn] = bf2f((unsigned)gb[tn * 16 + nl]);
#pragma unroll
  for (int tn = 0; tn < 2; ++tn) cb4[tn] = bf2f((unsigned)cb[tn * 16 + nl]);

  f32x4 hc0 = {0.f, 0.f, 0.f, 0.f}, hc1 = {0.f, 0.f, 0.f, 0.f};
  short8 hA = {0, 0, 0, 0, 0, 0, 0, 0};
  ushort_t* hb0 = hbuf[wv][0];
  ushort_t* hb1 = hbuf[wv][1];

  short8 afc[5], afn[5];
  gatherX(dir ? 20 : 0, btile, lane, tok_b, tok_a, cvt, typf, afc);

  for (int s = 0; s < 21; ++s) {
    const int t = dir ? 20 - s : s;
    if (s < 20)
      gatherX(dir ? t - 1 : t + 1, btile, lane, tok_b, tok_a, cvt, typf, afn);

    // gates
    f32x4 ru[4];
#pragma unroll
    for (int tn = 0; tn < 4; ++tn) {
      f32x4 acc = {gb4[tn], gb4[tn], gb4[tn], gb4[tn]};
#pragma unroll
      for (int kt = 0; kt < 5; ++kt) acc = mfma16(afc[kt], wg[kt][tn], acc);
      acc = mfma16(hA, wgh[tn], acc);
      ru[tn] = acc;
    }
#pragma unroll
    for (int tn = 0; tn < 4; ++tn)
#pragma unroll
      for (int r = 0; r < 4; ++r) ru[tn][r] = sgm(ru[tn][r]);

    // r*h -> packed A-layout (pi k-order): one cvt_pk + one b32 write per r
#pragma unroll
    for (int r = 0; r < 4; ++r)
      *reinterpret_cast<unsigned*>(hb0 + (q * 4 + r) * 40 + 2 * nl) =
          cvtpk(ru[0][r] * hc0[r], ru[1][r] * hc1[r]);
    short8 rhA = *reinterpret_cast<const short8*>(hb0 + nl * 40 + q * 8);

    // candidate
    f32x4 cc0 = {cb4[0], cb4[0], cb4[0], cb4[0]};
    f32x4 cc1 = {cb4[1], cb4[1], cb4[1], cb4[1]};
#pragma unroll
    for (int kt = 0; kt < 5; ++kt) {
      cc0 = mfma16(afc[kt], wc[kt][0], cc0);
      cc1 = mfma16(afc[kt], wc[kt][1], cc1);
    }
    cc0 = mfma16(rhA, wch[0], cc0);
    cc1 = mfma16(rhA, wch[1], cc1);
#pragma unroll
    for (int r = 0; r < 4; ++r) {
      const float c0 = tnh(cc0[r]), c1 = tnh(cc1[r]);
      const float u0 = ru[2][r], u1 = ru[3][r];
      hc0[r] = u0 * hc0[r] + (1.f - u0) * c0;
      hc1[r] = u1 * hc1[r] + (1.f - u1) * c1;
    }

    // h' -> packed A-layout (next operand + y0 output)
#pragma unroll
    for (int r = 0; r < 4; ++r)
      *reinterpret_cast<unsigned*>(hb1 + (q * 4 + r) * 40 + 2 * nl) =
          cvtpk(hc0[r], hc1[r]);
    hA = *reinterpret_cast<const short8*>(hb1 + nl * 40 + q * 8);
    y0a[((size_t)(t * 512 + btile) * 2 + dir) * 64 + lane] = __builtin_bit_cast(uint4, hA);

    if (s < 20) {
#pragma unroll
      for (int kt = 0; kt < 5; ++kt) afc[kt] = afn[kt];
    }
  }
}

// ---------------------------------------------------------------------------
// k3b: layer-1 recurrence (r13 structure) + diet. FP32 output [b][21][64].
// All L1 B-frags are pi-permuted (y0a and h are pi-packed).
// ---------------------------------------------------------------------------
__global__ __launch_bounds__(256, 1) void k3b(
    const ushort_t* __restrict__ cvt, const uint4* __restrict__ wf,
    const uint4* __restrict__ y0a, float* __restrict__ out) {
  __shared__ __align__(16) ushort_t hbuf[4][2][16 * 40];
  const int wv = threadIdx.x >> 6;
  const int lane = threadIdx.x & 63;
  const int q = lane >> 4, nl = lane & 15;
  const int job = blockIdx.x * 4 + wv;
  const int dir = job & 1, btile = job >> 1;

  const uint4* wfL1 = wf + (72 + dir * 18) * 64;
  short8 wg[3][4], wc[3][2];
#pragma unroll
  for (int kt = 0; kt < 3; ++kt) {
#pragma unroll
    for (int tn = 0; tn < 4; ++tn)
      wg[kt][tn] = __builtin_bit_cast(short8, wfL1[(kt * 4 + tn) * 64 + lane]);
#pragma unroll
    for (int tn = 0; tn < 2; ++tn)
      wc[kt][tn] = __builtin_bit_cast(short8, wfL1[(12 + kt * 2 + tn) * 64 + lane]);
  }
  const ushort_t* gb = cvt + (dir ? U_GBBW1 : U_GBFW1);
  const ushort_t* cb = cvt + (dir ? U_CBBW1 : U_CBFW1);
  float gb4[4], cb4[2];
#pragma unroll
  for (int tn = 0; tn < 4; ++tn) gb4[tn] = bf2f((unsigned)gb[tn * 16 + nl]);
#pragma unroll
  for (int tn = 0; tn < 2; ++tn) cb4[tn] = bf2f((unsigned)cb[tn * 16 + nl]);

  f32x4 hc0 = {0.f, 0.f, 0.f, 0.f}, hc1 = {0.f, 0.f, 0.f, 0.f};
  short8 hA = {0, 0, 0, 0, 0, 0, 0, 0};
  ushort_t* hb0 = hbuf[wv][0];
  ushort_t* hb1 = hbuf[wv][1];

  short8 ya0, ya1, yn0, yn1;
  {
    const int t0 = dir ? 20 : 0;
    ya0 = __builtin_bit_cast(short8, y0a[((size_t)(t0 * 512 + btile) * 2 + 0) * 64 + lane]);
    ya1 = __builtin_bit_cast(short8, y0a[((size_t)(t0 * 512 + btile) * 2 + 1) * 64 + lane]);
  }

  for (int s = 0; s < 21; ++s) {
    const int t = dir ? 20 - s : s;
    if (s < 20) {
      const int t2 = dir ? t - 1 : t + 1;
      yn0 = __builtin_bit_cast(short8, y0a[((size_t)(t2 * 512 + btile) * 2 + 0) * 64 + lane]);
      yn1 = __builtin_bit_cast(short8, y0a[((size_t)(t2 * 512 + btile) * 2 + 1) * 64 + lane]);
    }

    f32x4 ru[4];
#pragma unroll
    for (int tn = 0; tn < 4; ++tn) {
      f32x4 acc = {gb4[tn], gb4[tn], gb4[tn], gb4[tn]};
      acc = mfma16(ya0, wg[0][tn], acc);
      acc = mfma16(ya1, wg[1][tn], acc);
      acc = mfma16(hA,  wg[2][tn], acc);
      ru[tn] = acc;
    }
#pragma unroll
    for (int tn = 0; tn < 4; ++tn)
#pragma unroll
      for (int r = 0; r < 4; ++r) ru[tn][r] = sgm(ru[tn][r]);

#pragma unroll
    for (int r = 0; r < 4; ++r)
      *reinterpret_cast<unsigned*>(hb0 + (q * 4 + r) * 40 + 2 * nl) =
          cvtpk(ru[0][r] * hc0[r], ru[1][r] * hc1[r]);
    short8 rhA = *reinterpret_cast<const short8*>(hb0 + nl * 40 + q * 8);

    f32x4 cc0 = {cb4[0], cb4[0], cb4[0], cb4[0]};
    cc0 = mfma16(ya0, wc[0][0], cc0);
    cc0 = mfma16(ya1, wc[1][0], cc0);
    cc0 = mfma16(rhA, wc[2][0], cc0);
    f32x4 cc1 = {cb4[1], cb4[1], cb4[1], cb4[1]};
    cc1 = mfma16(ya0, wc[0][1], cc1);
    cc1 = mfma16(ya1, wc[1][1], cc1);
    cc1 = mfma16(rhA, wc[2][1], cc1);

#pragma unroll
    for (int r = 0; r < 4; ++r) {
      const float c0 = tnh(cc0[r]), c1 = tnh(cc1[r]);
      const float u0 = ru[2][r], u1 = ru[3][r];
      hc0[r] = u0 * hc0[r] + (1.f - u0) * c0;
      hc1[r] = u1 * hc1[r] + (1.f - u1) * c1;
    }

#pragma unroll
    for (int r = 0; r < 4; ++r)
      *reinterpret_cast<unsigned*>(hb1 + (q * 4 + r) * 40 + 2 * nl) =
          cvtpk(hc0[r], hc1[r]);
    hA = *reinterpret_cast<const short8*>(hb1 + nl * 40 + q * 8);

    // FP32 output: lane holds h'[m=q*4+r][ch nl and 16+nl] for this dir
#pragma unroll
    for (int r = 0; r < 4; ++r) {
      const size_t o = ((size_t)(btile * 16 + q * 4 + r) * 21 + t) * 64 + dir * 32 + nl;
      out[o]      = hc0[r];
      out[o + 16] = hc1[r];
    }

    if (s < 20) { ya0 = yn0; ya1 = yn1; }
  }
}

// ---------------------------------------------------------------------------
extern "C" void kernel_launch(void* const* d_in, const int* in_sizes, int n_in,
                              void* d_out, int out_size, void* d_ws, size_t ws_size,
                              hipStream_t stream)
{
  const int* tok_b = (const int*)d_in[0];
  const void* slot_tb = d_in[1];
  const void* slot_mb = d_in[2];
  const int* tok_a = (const int*)d_in[3];
  const void* slot_ta = d_in[4];
  const void* slot_ma = d_in[5];

  int* flags = (int*)d_ws;
  ushort_t* cvt = (ushort_t*)((char*)d_ws + 64);
  uint4* y0a = (uint4*)((char*)d_ws + Y0A_OFF);
  uint4* typf = (uint4*)((char*)d_ws + TYPF_OFF);
  uint4* wf  = (uint4*)((char*)d_ws + WF_OFF);

  k0_detect<<<dim3(1), dim3(64), 0, stream>>>(
      (const ushort_t*)d_in[6], (const unsigned*)slot_mb, (const unsigned*)slot_tb,
      flags);

  static const int slen[19] = {640000, 160000, 160,
                               12288, 64, 6144, 32, 12288, 64, 6144, 32,
                               6144, 64, 3072, 32, 6144, 64, 3072, 32};
  static const int sdst[19] = {U_TOKEMB, U_TYPEMB, U_HOLE,
                               U_GKFW0, U_GBFW0, U_CKFW0, U_CBFW0,
                               U_GKBW0, U_GBBW0, U_CKBW0, U_CBBW0,
                               U_GKFW1, U_GBFW1, U_CKFW1, U_CBFW1,
                               U_GKBW1, U_GBBW1, U_CKBW1, U_CBBW1};
  Cvt19 a;
  int tot = 0;
  for (int i = 0; i < 19; ++i) {
    a.src[i] = d_in[6 + i]; a.len[i] = slen[i]; a.dst[i] = sdst[i]; tot += slen[i];
  }
  kcvt<<<dim3((tot + 255) / 256), dim3(256), 0, stream>>>(a, cvt, flags);

  kswz<<<dim3(27), dim3(256), 0, stream>>>(cvt, wf);

  ktypmax<<<dim3(2560), dim3(256), 0, stream>>>(
      slot_tb, slot_mb, slot_ta, slot_ma, cvt, typf, flags);

  krec0<<<dim3(256), dim3(256), 0, stream>>>(tok_b, tok_a, cvt, wf, typf, y0a);

  k3b<<<dim3(256), dim3(256), 0, stream>>>(cvt, wf, y0a, (float*)d_out);
}